// Round 4
// baseline (1772.865 us; speedup 1.0000x reference)
//
#include <hip/hip_runtime.h>

#define NU 100000
#define D  64
#define NE 1600000

#define RPB 50                 // rows per bucket
#define NBK (NU / RPB)         // 2000 buckets (exact: 2000*50 = 100000)
#define NSUB (NBK * 8)         // 16000 sub-buckets (8 per bucket, keyed by blockIdx%8)
#define BINBLK 256             // block size for bhist/bin (must match between them)

__global__ void k_zero_i(int* __restrict__ p, int n) {
    int i = blockIdx.x * blockDim.x + threadIdx.x;
    if (i < n) p[i] = 0;
}

// histogram over (bucket, sub) where sub = (e>>8)&7 == blockIdx%8 with 256-thr blocks
__global__ void k_bhist(const int* __restrict__ rows, int* __restrict__ hist) {
    int e = blockIdx.x * BINBLK + threadIdx.x;
    if (e < NE) {
        int b = rows[e] / RPB;
        atomicAdd(&hist[b * 8 + (blockIdx.x & 7)], 1);
    }
}

// single-block exclusive scan of 16000 counters (1024 thr x 16 elems)
__global__ void k_bscan(const int* __restrict__ hist, int* __restrict__ base,
                        int* __restrict__ cursor) {
    __shared__ int part[1024];
    int t = threadIdx.x;
    int local[16];
    int s = 0;
    for (int k = 0; k < 16; ++k) {
        int idx = t * 16 + k;
        int v = (idx < NSUB) ? hist[idx] : 0;
        local[k] = s;
        s += v;
    }
    part[t] = s;
    __syncthreads();
    for (int off = 1; off < 1024; off <<= 1) {
        int x = (t >= off) ? part[t - off] : 0;
        __syncthreads();
        part[t] += x;
        __syncthreads();
    }
    int pre = part[t] - s;   // exclusive prefix of this thread's chunk
    for (int k = 0; k < 16; ++k) {
        int idx = t * 16 + k;
        if (idx < NSUB) {
            int v = pre + local[k];
            base[idx] = v;
            cursor[idx] = v;
        }
    }
    if (t == 1023) base[NSUB] = part[1023];   // == NE
}

// bin edges into (bucket, blockIdx%8) sub-buckets; row_local packed at bit 17
__global__ void k_bin(const int* __restrict__ rows, const int* __restrict__ cols,
                      const float* __restrict__ vals, int* __restrict__ cursor,
                      int2* __restrict__ bin) {
    int e = blockIdx.x * BINBLK + threadIdx.x;
    if (e >= NE) return;
    int r = rows[e];
    int b = r / RPB;
    int rl = r - b * RPB;                       // < 50, 6 bits
    int pos = atomicAdd(&cursor[b * 8 + (blockIdx.x & 7)], 1);
    bin[pos] = make_int2(cols[e] | (rl << 17), __float_as_int(vals[e]));   // col < 2^17
}

// One block per bucket: acc[50][64] in LDS, stream unsorted bucket edges with
// LDS fp32 atomics, then write the 50 output rows coalesced.
// FINAL=0: dst = acc (layer buffer).  FINAL=1: dst = emb + pA + pB + acc.
template <int FINAL>
__global__ void k_bgather(const int2* __restrict__ bin, const int* __restrict__ base,
                          const float* __restrict__ x, const float* __restrict__ emb,
                          const float* __restrict__ pA, const float* __restrict__ pB,
                          float* __restrict__ dst) {
    __shared__ float acc[RPB][D];   // 12.8 KB
    int b = blockIdx.x;
    int start = base[b * 8];
    int end   = base[b * 8 + 8];    // sub-buckets are adjacent -> contiguous range
    int t = threadIdx.x;

    for (int i = t; i < RPB * D; i += 256) ((float*)acc)[i] = 0.f;
    __syncthreads();

    int wid = t >> 6, lane = t & 63;
    int n = end - start;
    int chunk = (n + 3) >> 2;                 // 4 waves per block
    int ws = start + wid * chunk;
    int we = ws + chunk; if (we > end) we = end;

#pragma unroll 4
    for (int i = ws; i < we; ++i) {
        int2 e = bin[i];                      // wave-uniform 8B load
        int rl  = e.x >> 17;
        int col = e.x & 0x1FFFF;
        float v = __int_as_float(e.y);
        atomicAdd(&acc[rl][lane], v * x[(col << 6) + lane]);
    }
    __syncthreads();

    int rowbase = b * RPB;
    for (int rl = wid; rl < RPB; rl += 4) {
        int o = (rowbase + rl) * D + lane;
        float a = acc[rl][lane];
        if (FINAL) dst[o] = emb[o] + pA[o] + pB[o] + a;
        else       dst[o] = a;
    }
}

extern "C" void kernel_launch(void* const* d_in, const int* in_sizes, int n_in,
                              void* d_out, int out_size, void* d_ws, size_t ws_size,
                              hipStream_t stream) {
    const int*   rows = (const int*)d_in[0];
    const int*   cols = (const int*)d_in[1];
    const float* vals = (const float*)d_in[2];
    const float* emb  = (const float*)d_in[3];
    float* out = (float*)d_out;

    // workspace layout (~64.2 MB)
    float* bufA   = (float*)d_ws;                    // NU*D floats (25.6 MB)
    float* bufB   = bufA + (size_t)NU * D;           // NU*D floats (25.6 MB)
    int2*  bin    = (int2*)(bufB + (size_t)NU * D);  // NE int2 (12.8 MB)
    int*   hist   = (int*)(bin + NE);                // NSUB
    int*   base   = hist + NSUB;                     // NSUB+1
    int*   cursor = base + NSUB + 1;                 // NSUB

    const int gE = (NE + BINBLK - 1) / BINBLK;       // 6250 (same for bhist & bin!)

    // --- bucket-bin the edges (no full sort needed) ---
    k_zero_i<<<(NSUB + 255) / 256, 256, 0, stream>>>(hist, NSUB);
    k_bhist<<<gE, BINBLK, 0, stream>>>(rows, hist);
    k_bscan<<<1, 1024, 0, stream>>>(hist, base, cursor);
    k_bin<<<gE, BINBLK, 0, stream>>>(rows, cols, vals, cursor, bin);

    // --- 3 bucket-gather SpMM layers; final layer fuses the output sum ---
    k_bgather<0><<<NBK, 256, 0, stream>>>(bin, base, emb,  emb, bufA, bufB, bufA);
    k_bgather<0><<<NBK, 256, 0, stream>>>(bin, base, bufA, emb, bufA, bufB, bufB);
    k_bgather<1><<<NBK, 256, 0, stream>>>(bin, base, bufB, emb, bufA, bufB, out);
}

// Round 5
// 348.173 us; speedup vs baseline: 5.0919x; 5.0919x over previous
//
#include <hip/hip_runtime.h>

#define NU 100000
#define D  64
#define NE 1600000

#define RPB 50                 // rows per bucket
#define NBK (NU / RPB)         // 2000 buckets
#define NSUB (NBK * 8)         // 8 XCD-keyed sub-buckets per bucket
#define BINBLK 256

__global__ void k_zero_i(int* __restrict__ p, int n) {
    int i = blockIdx.x * blockDim.x + threadIdx.x;
    if (i < n) p[i] = 0;
}

// histogram over (bucket, blockIdx%8)
__global__ void k_bhist(const int* __restrict__ rows, int* __restrict__ hist) {
    int e = blockIdx.x * BINBLK + threadIdx.x;
    if (e < NE) {
        int b = rows[e] / RPB;
        atomicAdd(&hist[b * 8 + (blockIdx.x & 7)], 1);
    }
}

// single-block exclusive scan of 16000 counters (1024 thr x 16)
__global__ void k_bscan(const int* __restrict__ hist, int* __restrict__ base,
                        int* __restrict__ cursor) {
    __shared__ int part[1024];
    int t = threadIdx.x;
    int local[16];
    int s = 0;
    for (int k = 0; k < 16; ++k) {
        int idx = t * 16 + k;
        int v = (idx < NSUB) ? hist[idx] : 0;
        local[k] = s;
        s += v;
    }
    part[t] = s;
    __syncthreads();
    for (int off = 1; off < 1024; off <<= 1) {
        int x = (t >= off) ? part[t - off] : 0;
        __syncthreads();
        part[t] += x;
        __syncthreads();
    }
    int pre = part[t] - s;
    for (int k = 0; k < 16; ++k) {
        int idx = t * 16 + k;
        if (idx < NSUB) {
            int v = pre + local[k];
            base[idx] = v;
            cursor[idx] = v;
        }
    }
    if (t == 1023) base[NSUB] = part[1023];   // == NE
}

// bin edges into (bucket, blockIdx%8) sub-buckets; row_local packed at bit 17
__global__ void k_bin(const int* __restrict__ rows, const int* __restrict__ cols,
                      const float* __restrict__ vals, int* __restrict__ cursor,
                      int2* __restrict__ bin) {
    int e = blockIdx.x * BINBLK + threadIdx.x;
    if (e >= NE) return;
    int r = rows[e];
    int b = r / RPB;
    int rl = r - b * RPB;                        // < 50
    int pos = atomicAdd(&cursor[b * 8 + (blockIdx.x & 7)], 1);
    bin[pos] = make_int2(cols[e] | (rl << 17), __float_as_int(vals[e]));  // col < 2^17
}

// per-bucket CSR-ify: count rows locally, scan, scatter into the bucket's
// contiguous CSR slice (stays in this XCD's L2 -> no write amplification).
// Also emits rowptr (NU+1).
__global__ void k_bsort(const int2* __restrict__ bin, const int* __restrict__ base,
                        int2* __restrict__ edges, int* __restrict__ rowptr) {
    __shared__ int cnt[RPB];
    __shared__ int pref[RPB + 1];
    int b = blockIdx.x;
    int start = base[b * 8];
    int end   = base[b * 8 + 8];
    int t = threadIdx.x;
    if (t < RPB) cnt[t] = 0;
    __syncthreads();
    for (int i = start + t; i < end; i += 256)
        atomicAdd(&cnt[bin[i].x >> 17], 1);
    __syncthreads();
    if (t == 0) {
        int s = 0;
        for (int k = 0; k < RPB; ++k) { pref[k] = s; s += cnt[k]; }
        pref[RPB] = s;
    }
    __syncthreads();
    if (t < RPB) rowptr[b * RPB + t] = start + pref[t];
    if (b == NBK - 1 && t == 0) rowptr[NU] = end;
    if (t < RPB) cnt[t] = pref[t];    // reuse as cursor
    __syncthreads();
    for (int i = start + t; i < end; i += 256) {
        int2 ed = bin[i];
        int rl = ed.x >> 17;
        int pos = start + atomicAdd(&cnt[rl], 1);
        edges[pos] = make_int2(ed.x & 0x1FFFF, ed.y);
    }
}

__device__ __forceinline__ void fma4(float4& a, float v, const float4& x) {
    a.x += v * x.x; a.y += v * x.y; a.z += v * x.z; a.w += v * x.w;
}

// One 64-lane wave per row. 4 edges processed simultaneously (16 lanes x float4
// each -> one dwordx4 covers a 256B x-row), 8 edges (2 quads) in flight.
// Cross-group reduce via shfl_xor(16,32).
// FINAL=0: dst = acc.  FINAL=1: dst = emb + pA + pB + acc.
template <int FINAL>
__global__ void k_gather(const int2* __restrict__ edges, const int* __restrict__ rowptr,
                         const float4* __restrict__ x4, const float4* __restrict__ emb4,
                         const float4* __restrict__ pA4, const float4* __restrict__ pB4,
                         float4* __restrict__ dst4) {
    int r = blockIdx.x * 4 + (threadIdx.x >> 6);
    if (r >= NU) return;
    int lane = threadIdx.x & 63;
    int g = lane >> 4;          // which edge of the quad
    int sub = lane & 15;        // float4 slot within the row
    int start = rowptr[r];
    int end   = rowptr[r + 1];
    int len   = end - start;
    int n0 = len < 64 ? len : 64;

    int2 my = make_int2(0, 0);
    if (lane < n0) my = edges[start + lane];

    float4 a0 = {0.f,0.f,0.f,0.f}, a1 = {0.f,0.f,0.f,0.f};
    int i = 0;
    for (; i + 8 <= n0; i += 8) {
        int   c0 = __shfl(my.x, i + g, 64);
        float v0 = __int_as_float(__shfl(my.y, i + g, 64));
        int   c1 = __shfl(my.x, i + 4 + g, 64);
        float v1 = __int_as_float(__shfl(my.y, i + 4 + g, 64));
        float4 x0 = x4[(size_t)c0 * 16 + sub];
        float4 x1 = x4[(size_t)c1 * 16 + sub];
        fma4(a0, v0, x0);
        fma4(a1, v1, x1);
    }
    for (; i < n0; i += 4) {                  // masked tail quads (<= 2 iters)
        int e = i + g;
        int es = e < n0 ? e : 0;
        int   c = __shfl(my.x, es, 64);
        float v = __int_as_float(__shfl(my.y, es, 64));
        if (e >= n0) v = 0.f;
        float4 xv = x4[(size_t)c * 16 + sub];
        fma4(a0, v, xv);
    }
    // safety: rows with >64 edges (effectively never at E/U=16)
    for (int j = start + 64; j < end; ++j) {
        int2 ed = edges[j];
        if (g == 0) {
            float4 xv = x4[(size_t)ed.x * 16 + sub];
            fma4(a0, __int_as_float(ed.y), xv);
        }
    }

    float4 s;
    s.x = a0.x + a1.x; s.y = a0.y + a1.y; s.z = a0.z + a1.z; s.w = a0.w + a1.w;
    for (int mask = 16; mask < 64; mask <<= 1) {
        s.x += __shfl_xor(s.x, mask, 64);
        s.y += __shfl_xor(s.y, mask, 64);
        s.z += __shfl_xor(s.z, mask, 64);
        s.w += __shfl_xor(s.w, mask, 64);
    }

    if (g == 0) {
        size_t o = (size_t)r * 16 + sub;
        float4 res = s;
        if (FINAL) {
            float4 e = emb4[o], A = pA4[o], B = pB4[o];
            res.x += e.x + A.x + B.x;
            res.y += e.y + A.y + B.y;
            res.z += e.z + A.z + B.z;
            res.w += e.w + A.w + B.w;
        }
        dst4[o] = res;
    }
}

extern "C" void kernel_launch(void* const* d_in, const int* in_sizes, int n_in,
                              void* d_out, int out_size, void* d_ws, size_t ws_size,
                              hipStream_t stream) {
    const int*   rows = (const int*)d_in[0];
    const int*   cols = (const int*)d_in[1];
    const float* vals = (const float*)d_in[2];
    const float* emb  = (const float*)d_in[3];
    float* out = (float*)d_out;

    // workspace layout (~77.5 MB)
    float* bufA   = (float*)d_ws;                     // NU*D floats (25.6 MB)
    float* bufB   = bufA + (size_t)NU * D;            // NU*D floats (25.6 MB)
    int2*  bin    = (int2*)(bufB + (size_t)NU * D);   // NE int2 (12.8 MB)
    int2*  edges  = bin + NE;                         // NE int2 (12.8 MB)
    int*   hist   = (int*)(edges + NE);               // NSUB
    int*   base   = hist + NSUB;                      // NSUB+1
    int*   cursor = base + NSUB + 1;                  // NSUB
    int*   rowptr = cursor + NSUB;                    // NU+1

    const int gE = (NE + BINBLK - 1) / BINBLK;

    // --- CSR build: bin (XCD-keyed) + per-bucket sort ---
    k_zero_i<<<(NSUB + 255) / 256, 256, 0, stream>>>(hist, NSUB);
    k_bhist<<<gE, BINBLK, 0, stream>>>(rows, hist);
    k_bscan<<<1, 1024, 0, stream>>>(hist, base, cursor);
    k_bin<<<gE, BINBLK, 0, stream>>>(rows, cols, vals, cursor, bin);
    k_bsort<<<NBK, 256, 0, stream>>>(bin, base, edges, rowptr);

    // --- 3 gather-SpMM layers; final fuses out = emb + l1 + l2 + l3 ---
    const float4* emb4 = (const float4*)emb;
    float4* A4 = (float4*)bufA;
    float4* B4 = (float4*)bufB;
    const int gG = NU / 4;   // 25000
    k_gather<0><<<gG, 256, 0, stream>>>(edges, rowptr, emb4,              emb4, A4, B4, A4);
    k_gather<0><<<gG, 256, 0, stream>>>(edges, rowptr, (const float4*)A4, emb4, A4, B4, B4);
    k_gather<1><<<gG, 256, 0, stream>>>(edges, rowptr, (const float4*)B4, emb4, A4, B4, (float4*)out);
}

// Round 7
// 218.876 us; speedup vs baseline: 8.0998x; 1.5907x over previous
//
#include <hip/hip_runtime.h>

#define NU 100000
#define D  64
#define NE 1600000

#define RPB 50                  // rows per bucket
#define NBK (NU / RPB)          // 2000 buckets
#define SUBCAP 192              // capacity per (bucket, xcd) sub-chunk (mean 102, ~9 sigma)
#define BCAP (SUBCAP * 8)       // 1536 edge slots per bucket
#define NSUB (NBK * 8)          // 16000
#define EPB 8192                // edges per k_bin2 block
#define BIN_BLOCKS ((NE + EPB - 1) / EPB)   // 196

__global__ void k_zero_i(int* __restrict__ p, int n) {
    int i = blockIdx.x * blockDim.x + threadIdx.x;
    if (i < n) p[i] = 0;
}

// Aggregated-claim binning: LDS histogram over 2000 buckets -> one global
// atomic per (block, bucket) -> LDS-atomic per-edge position handout.
// Sub-chunk keyed by blockIdx%8 (XCD heuristic); cursor is s-major.
__global__ __launch_bounds__(512) void k_bin2(const int* __restrict__ rows,
                                              const int* __restrict__ cols,
                                              const float* __restrict__ vals,
                                              int* __restrict__ cursor,
                                              int2* __restrict__ bin) {
    __shared__ int hist[NBK];
    __shared__ int base[NBK];
    int t = threadIdx.x;
    int s = blockIdx.x & 7;
    int e0 = blockIdx.x * EPB;

    for (int b = t; b < NBK; b += 512) hist[b] = 0;
    __syncthreads();

    int rloc[16];
#pragma unroll
    for (int j = 0; j < 16; ++j) {
        int e = e0 + j * 512 + t;
        int r = (e < NE) ? rows[e] : -1;
        rloc[j] = r;
        if (r >= 0) atomicAdd(&hist[r / RPB], 1);
    }
    __syncthreads();

    for (int b = t; b < NBK; b += 512) {
        int h = hist[b];
        int claim = (h > 0) ? atomicAdd(&cursor[s * NBK + b], h) : 0;
        base[b] = b * BCAP + s * SUBCAP + claim;
    }
    __syncthreads();

#pragma unroll
    for (int j = 0; j < 16; ++j) {
        int e = e0 + j * 512 + t;
        if (e < NE) {
            int r  = rloc[j];
            int b  = r / RPB;
            int rl = r - b * RPB;                  // < 50
            int pos = atomicAdd(&base[b], 1);      // LDS atomic -> global slot
            bin[pos] = make_int2(cols[e] | (rl << 17), __float_as_int(vals[e]));
        }
    }
}

// Per-bucket row sort, in place: stage bucket edges in LDS (all reads complete
// before the barrier; writes only after), count rows, scan, write the
// row-sorted list back into the same bucket region. Emits rowstart/rowend.
__global__ __launch_bounds__(256) void k_bsort(int2* __restrict__ bin,
                                               const int* __restrict__ cursor,
                                               int* __restrict__ rowstart,
                                               int* __restrict__ rowend) {
    __shared__ int2 stage[BCAP];          // 12.3 KB
    __shared__ int scnt[8], soff[9];
    __shared__ int cnt[RPB], pref[RPB + 1], cur[RPB];
    int b = blockIdx.x;
    int t = threadIdx.x;

    if (t < 8) {
        int c = cursor[t * NBK + b];
        scnt[t] = c < SUBCAP ? c : SUBCAP;    // defensive clamp (no-op in practice)
    }
    if (t < RPB) cnt[t] = 0;
    __syncthreads();
    if (t == 0) {
        int s = 0;
        for (int k = 0; k < 8; ++k) { soff[k] = s; s += scnt[k]; }
        soff[8] = s;
    }
    __syncthreads();

    for (int s = 0; s < 8; ++s) {
        int c = scnt[s];
        const int2* src = bin + (size_t)b * BCAP + s * SUBCAP;
        int o = soff[s];
        for (int i = t; i < c; i += 256) {
            int2 ed = src[i];
            stage[o + i] = ed;
            atomicAdd(&cnt[ed.x >> 17], 1);
        }
    }
    __syncthreads();
    if (t == 0) {
        int s = 0;
        for (int k = 0; k < RPB; ++k) { pref[k] = s; s += cnt[k]; }
        pref[RPB] = s;
    }
    __syncthreads();
    if (t < RPB) {
        rowstart[b * RPB + t] = b * BCAP + pref[t];
        rowend[b * RPB + t]   = b * BCAP + pref[t + 1];
        cur[t] = pref[t];
    }
    __syncthreads();
    int tot = soff[8];
    for (int i = t; i < tot; i += 256) {
        int2 ed = stage[i];
        int rl = ed.x >> 17;
        int p = atomicAdd(&cur[rl], 1);
        bin[(size_t)b * BCAP + p] = make_int2(ed.x & 0x1FFFF, ed.y);
    }
}

__device__ __forceinline__ void fma4(float4& a, float v, const float4& x) {
    a.x += v * x.x; a.y += v * x.y; a.z += v * x.z; a.w += v * x.w;
}

// R4-proven gather: one 64-lane wave per row, 4 edges at a time (16 lanes x
// float4 each), 8 edges (2 quads) in flight; shfl_xor(16,32) reduce.
// Only change vs R4: start/end come from rowstart/rowend arrays.
// FINAL=0: dst = acc.  FINAL=1: dst = emb + pA + pB + acc.
template <int FINAL>
__global__ __launch_bounds__(256) void k_gather(const int2* __restrict__ edges,
                                                const int* __restrict__ rowstart,
                                                const int* __restrict__ rowend,
                                                const float4* __restrict__ x4,
                                                const float4* __restrict__ emb4,
                                                const float4* __restrict__ pA4,
                                                const float4* __restrict__ pB4,
                                                float4* __restrict__ dst4) {
    int r = blockIdx.x * 4 + (threadIdx.x >> 6);
    if (r >= NU) return;
    int lane = threadIdx.x & 63;
    int g = lane >> 4;          // which edge of the quad
    int sub = lane & 15;        // float4 slot within the row
    int start = rowstart[r];
    int end   = rowend[r];
    int len   = end - start;
    int n0 = len < 64 ? len : 64;

    int2 my = make_int2(0, 0);
    if (lane < n0) my = edges[start + lane];

    float4 a0 = {0.f,0.f,0.f,0.f}, a1 = {0.f,0.f,0.f,0.f};
    int i = 0;
    for (; i + 8 <= n0; i += 8) {
        int   c0 = __shfl(my.x, i + g, 64);
        float v0 = __int_as_float(__shfl(my.y, i + g, 64));
        int   c1 = __shfl(my.x, i + 4 + g, 64);
        float v1 = __int_as_float(__shfl(my.y, i + 4 + g, 64));
        float4 x0 = x4[(size_t)c0 * 16 + sub];
        float4 x1 = x4[(size_t)c1 * 16 + sub];
        fma4(a0, v0, x0);
        fma4(a1, v1, x1);
    }
    for (; i < n0; i += 4) {                  // masked tail quads (<= 2 iters)
        int e = i + g;
        int es = e < n0 ? e : 0;
        int   c = __shfl(my.x, es, 64);
        float v = __int_as_float(__shfl(my.y, es, 64));
        if (e >= n0) v = 0.f;
        float4 xv = x4[(size_t)c * 16 + sub];
        fma4(a0, v, xv);
    }
    // safety: rows with >64 edges (effectively never at E/U = 16)
    for (int j = start + 64; j < end; ++j) {
        int2 ed = edges[j];
        if (g == 0) {
            float4 xv = x4[(size_t)ed.x * 16 + sub];
            fma4(a0, __int_as_float(ed.y), xv);
        }
    }

    float4 s;
    s.x = a0.x + a1.x; s.y = a0.y + a1.y; s.z = a0.z + a1.z; s.w = a0.w + a1.w;
    for (int mask = 16; mask < 64; mask <<= 1) {
        s.x += __shfl_xor(s.x, mask, 64);
        s.y += __shfl_xor(s.y, mask, 64);
        s.z += __shfl_xor(s.z, mask, 64);
        s.w += __shfl_xor(s.w, mask, 64);
    }

    if (g == 0) {
        size_t o = (size_t)r * 16 + sub;
        float4 res = s;
        if (FINAL) {
            float4 e = emb4[o], A = pA4[o], B = pB4[o];
            res.x += e.x + A.x + B.x;
            res.y += e.y + A.y + B.y;
            res.z += e.z + A.z + B.z;
            res.w += e.w + A.w + B.w;
        }
        dst4[o] = res;
    }
}

extern "C" void kernel_launch(void* const* d_in, const int* in_sizes, int n_in,
                              void* d_out, int out_size, void* d_ws, size_t ws_size,
                              hipStream_t stream) {
    const int*   rows = (const int*)d_in[0];
    const int*   cols = (const int*)d_in[1];
    const float* vals = (const float*)d_in[2];
    const float* emb  = (const float*)d_in[3];
    float* out = (float*)d_out;

    // workspace layout (~76.6 MB; R4 proved >= 77.7 MB available)
    float* bufA     = (float*)d_ws;                     // NU*D floats (25.6 MB)
    float* bufB     = bufA + (size_t)NU * D;            // NU*D floats (25.6 MB)
    int2*  bin      = (int2*)(bufB + (size_t)NU * D);   // NBK*BCAP int2 (24.6 MB)
    int*   cursor   = (int*)(bin + (size_t)NBK * BCAP); // NSUB
    int*   rowstart = cursor + NSUB;                    // NU
    int*   rowend   = rowstart + NU;                    // NU

    // --- CSR build: aggregated-claim bin + in-place per-bucket row sort ---
    k_zero_i<<<(NSUB + 255) / 256, 256, 0, stream>>>(cursor, NSUB);
    k_bin2<<<BIN_BLOCKS, 512, 0, stream>>>(rows, cols, vals, cursor, bin);
    k_bsort<<<NBK, 256, 0, stream>>>(bin, cursor, rowstart, rowend);

    // --- 3 gather-SpMM layers; final fuses out = emb + l1 + l2 + l3 ---
    const float4* emb4 = (const float4*)emb;
    float4* A4 = (float4*)bufA;
    float4* B4 = (float4*)bufB;
    const int gG = NU / 4;   // 25000
    k_gather<0><<<gG, 256, 0, stream>>>(bin, rowstart, rowend, emb4,              emb4, A4, B4, A4);
    k_gather<0><<<gG, 256, 0, stream>>>(bin, rowstart, rowend, (const float4*)A4, emb4, A4, B4, B4);
    k_gather<1><<<gG, 256, 0, stream>>>(bin, rowstart, rowend, (const float4*)B4, emb4, A4, B4, (float4*)out);
}

// Round 8
// 218.576 us; speedup vs baseline: 8.1110x; 1.0014x over previous
//
#include <hip/hip_runtime.h>

#define NU 100000
#define D  64
#define NE 1600000

#define RPB 50                  // rows per bucket
#define NBK (NU / RPB)          // 2000 buckets
#define SUBCAP 192              // capacity per (bucket, xcd) sub-chunk (mean 102, ~9 sigma)
#define BCAP (SUBCAP * 8)       // 1536 edge slots per bucket
#define NSUB (NBK * 8)          // 16000
#define EPB 8192                // edges per k_bin2 block
#define BIN_BLOCKS ((NE + EPB - 1) / EPB)   // 196

__global__ void k_zero_i(int* __restrict__ p, int n) {
    int i = blockIdx.x * blockDim.x + threadIdx.x;
    if (i < n) p[i] = 0;
}

// Aggregated-claim binning: LDS histogram over 2000 buckets -> one global
// atomic per (block, bucket) -> LDS-atomic per-edge position handout.
// Sub-chunk keyed by blockIdx%8 (XCD heuristic); cursor is s-major.
__global__ __launch_bounds__(512) void k_bin2(const int* __restrict__ rows,
                                              const int* __restrict__ cols,
                                              const float* __restrict__ vals,
                                              int* __restrict__ cursor,
                                              int2* __restrict__ bin) {
    __shared__ int hist[NBK];
    __shared__ int base[NBK];
    int t = threadIdx.x;
    int s = blockIdx.x & 7;
    int e0 = blockIdx.x * EPB;

    for (int b = t; b < NBK; b += 512) hist[b] = 0;
    __syncthreads();

    int rloc[16];
#pragma unroll
    for (int j = 0; j < 16; ++j) {
        int e = e0 + j * 512 + t;
        int r = (e < NE) ? rows[e] : -1;
        rloc[j] = r;
        if (r >= 0) atomicAdd(&hist[r / RPB], 1);
    }
    __syncthreads();

    for (int b = t; b < NBK; b += 512) {
        int h = hist[b];
        int claim = (h > 0) ? atomicAdd(&cursor[s * NBK + b], h) : 0;
        base[b] = b * BCAP + s * SUBCAP + claim;
    }
    __syncthreads();

#pragma unroll
    for (int j = 0; j < 16; ++j) {
        int e = e0 + j * 512 + t;
        if (e < NE) {
            int r  = rloc[j];
            int b  = r / RPB;
            int rl = r - b * RPB;                  // < 50
            int pos = atomicAdd(&base[b], 1);      // LDS atomic -> global slot
            bin[pos] = make_int2(cols[e] | (rl << 17), __float_as_int(vals[e]));
        }
    }
}

// Per-bucket row sort, in place: stage bucket edges in LDS (all reads complete
// before the barrier; writes only after), count rows, scan, write the
// row-sorted list back into the same bucket region. Emits rowstart/rowend.
__global__ __launch_bounds__(256) void k_bsort(int2* __restrict__ bin,
                                               const int* __restrict__ cursor,
                                               int* __restrict__ rowstart,
                                               int* __restrict__ rowend) {
    __shared__ int2 stage[BCAP];          // 12.3 KB
    __shared__ int scnt[8], soff[9];
    __shared__ int cnt[RPB], pref[RPB + 1], cur[RPB];
    int b = blockIdx.x;
    int t = threadIdx.x;

    if (t < 8) {
        int c = cursor[t * NBK + b];
        scnt[t] = c < SUBCAP ? c : SUBCAP;    // defensive clamp (no-op in practice)
    }
    if (t < RPB) cnt[t] = 0;
    __syncthreads();
    if (t == 0) {
        int s = 0;
        for (int k = 0; k < 8; ++k) { soff[k] = s; s += scnt[k]; }
        soff[8] = s;
    }
    __syncthreads();

    for (int s = 0; s < 8; ++s) {
        int c = scnt[s];
        const int2* src = bin + (size_t)b * BCAP + s * SUBCAP;
        int o = soff[s];
        for (int i = t; i < c; i += 256) {
            int2 ed = src[i];
            stage[o + i] = ed;
            atomicAdd(&cnt[ed.x >> 17], 1);
        }
    }
    __syncthreads();
    if (t == 0) {
        int s = 0;
        for (int k = 0; k < RPB; ++k) { pref[k] = s; s += cnt[k]; }
        pref[RPB] = s;
    }
    __syncthreads();
    if (t < RPB) {
        rowstart[b * RPB + t] = b * BCAP + pref[t];
        rowend[b * RPB + t]   = b * BCAP + pref[t + 1];
        cur[t] = pref[t];
    }
    __syncthreads();
    int tot = soff[8];
    for (int i = t; i < tot; i += 256) {
        int2 ed = stage[i];
        int rl = ed.x >> 17;
        int p = atomicAdd(&cur[rl], 1);
        bin[(size_t)b * BCAP + p] = make_int2(ed.x & 0x1FFFF, ed.y);
    }
}

__device__ __forceinline__ void fma4(float4& a, float v, const float4& x) {
    a.x += v * x.x; a.y += v * x.y; a.z += v * x.z; a.w += v * x.w;
}

// One 64-lane wave per row; 4 edges at a time (16 lanes x float4 each).
// Main loop: 4 quads (16 edges, 16 independent dwordx4) in flight.
// Tail: R4/R6-proven masked single quad. shfl_xor(16,32) reduce.
// FINAL=0: dst = acc.  FINAL=1: dst = emb + pA + pB + acc.
template <int FINAL>
__global__ __launch_bounds__(256) void k_gather(const int2* __restrict__ edges,
                                                const int* __restrict__ rowstart,
                                                const int* __restrict__ rowend,
                                                const float4* __restrict__ x4,
                                                const float4* __restrict__ emb4,
                                                const float4* __restrict__ pA4,
                                                const float4* __restrict__ pB4,
                                                float4* __restrict__ dst4) {
    int r = blockIdx.x * 4 + (threadIdx.x >> 6);
    if (r >= NU) return;
    int lane = threadIdx.x & 63;
    int g = lane >> 4;          // which edge of the quad
    int sub = lane & 15;        // float4 slot within the row
    int start = rowstart[r];
    int end   = rowend[r];
    int len   = end - start;
    int n0 = len < 64 ? len : 64;

    int2 my = make_int2(0, 0);
    if (lane < n0) my = edges[start + lane];

    float4 a0 = {0.f,0.f,0.f,0.f}, a1 = {0.f,0.f,0.f,0.f};
    float4 a2 = {0.f,0.f,0.f,0.f}, a3 = {0.f,0.f,0.f,0.f};
    int i = 0;
    for (; i + 16 <= n0; i += 16) {
        int   c0 = __shfl(my.x, i + g,      64);
        int   c1 = __shfl(my.x, i + 4 + g,  64);
        int   c2 = __shfl(my.x, i + 8 + g,  64);
        int   c3 = __shfl(my.x, i + 12 + g, 64);
        float v0 = __int_as_float(__shfl(my.y, i + g,      64));
        float v1 = __int_as_float(__shfl(my.y, i + 4 + g,  64));
        float v2 = __int_as_float(__shfl(my.y, i + 8 + g,  64));
        float v3 = __int_as_float(__shfl(my.y, i + 12 + g, 64));
        float4 x0 = x4[(size_t)c0 * 16 + sub];
        float4 x1 = x4[(size_t)c1 * 16 + sub];
        float4 x2 = x4[(size_t)c2 * 16 + sub];
        float4 x3 = x4[(size_t)c3 * 16 + sub];
        fma4(a0, v0, x0);
        fma4(a1, v1, x1);
        fma4(a2, v2, x2);
        fma4(a3, v3, x3);
    }
    for (; i < n0; i += 4) {                  // masked tail quads (R4-proven)
        int e = i + g;
        int es = e < n0 ? e : 0;
        int   c = __shfl(my.x, es, 64);
        float v = __int_as_float(__shfl(my.y, es, 64));
        if (e >= n0) v = 0.f;
        float4 xv = x4[(size_t)c * 16 + sub];
        fma4(a0, v, xv);
    }
    // safety: rows with >64 edges (effectively never at E/U = 16)
    for (int j = start + 64; j < end; ++j) {
        int2 ed = edges[j];
        if (g == 0) {
            float4 xv = x4[(size_t)ed.x * 16 + sub];
            fma4(a0, __int_as_float(ed.y), xv);
        }
    }

    float4 s;
    s.x = (a0.x + a1.x) + (a2.x + a3.x);
    s.y = (a0.y + a1.y) + (a2.y + a3.y);
    s.z = (a0.z + a1.z) + (a2.z + a3.z);
    s.w = (a0.w + a1.w) + (a2.w + a3.w);
    for (int mask = 16; mask < 64; mask <<= 1) {
        s.x += __shfl_xor(s.x, mask, 64);
        s.y += __shfl_xor(s.y, mask, 64);
        s.z += __shfl_xor(s.z, mask, 64);
        s.w += __shfl_xor(s.w, mask, 64);
    }

    if (g == 0) {
        size_t o = (size_t)r * 16 + sub;
        float4 res = s;
        if (FINAL) {
            float4 e = emb4[o], A = pA4[o], B = pB4[o];
            res.x += e.x + A.x + B.x;
            res.y += e.y + A.y + B.y;
            res.z += e.z + A.z + B.z;
            res.w += e.w + A.w + B.w;
        }
        dst4[o] = res;
    }
}

extern "C" void kernel_launch(void* const* d_in, const int* in_sizes, int n_in,
                              void* d_out, int out_size, void* d_ws, size_t ws_size,
                              hipStream_t stream) {
    const int*   rows = (const int*)d_in[0];
    const int*   cols = (const int*)d_in[1];
    const float* vals = (const float*)d_in[2];
    const float* emb  = (const float*)d_in[3];
    float* out = (float*)d_out;

    // workspace layout (~76.6 MB)
    float* bufA     = (float*)d_ws;                     // NU*D floats (25.6 MB)
    float* bufB     = bufA + (size_t)NU * D;            // NU*D floats (25.6 MB)
    int2*  bin      = (int2*)(bufB + (size_t)NU * D);   // NBK*BCAP int2 (24.6 MB)
    int*   cursor   = (int*)(bin + (size_t)NBK * BCAP); // NSUB
    int*   rowstart = cursor + NSUB;                    // NU
    int*   rowend   = rowstart + NU;                    // NU

    // --- CSR build: aggregated-claim bin + in-place per-bucket row sort ---
    k_zero_i<<<(NSUB + 255) / 256, 256, 0, stream>>>(cursor, NSUB);
    k_bin2<<<BIN_BLOCKS, 512, 0, stream>>>(rows, cols, vals, cursor, bin);
    k_bsort<<<NBK, 256, 0, stream>>>(bin, cursor, rowstart, rowend);

    // --- 3 gather-SpMM layers; final fuses out = emb + l1 + l2 + l3 ---
    const float4* emb4 = (const float4*)emb;
    float4* A4 = (float4*)bufA;
    float4* B4 = (float4*)bufB;
    const int gG = NU / 4;   // 25000
    k_gather<0><<<gG, 256, 0, stream>>>(bin, rowstart, rowend, emb4,              emb4, A4, B4, A4);
    k_gather<0><<<gG, 256, 0, stream>>>(bin, rowstart, rowend, (const float4*)A4, emb4, A4, B4, B4);
    k_gather<1><<<gG, 256, 0, stream>>>(bin, rowstart, rowend, (const float4*)B4, emb4, A4, B4, (float4*)out);
}